// Round 6
// baseline (100.196 us; speedup 1.0000x reference)
//
#include <hip/hip_runtime.h>

// probs = |U^{x8} f|^2 / ||f||^2, U = 8x8 complex gate on each of 8 qubit triples.
// MFMA: per 3-qubit axis, D = A*B, A(16x16 f16) = [[Gr,-Gi],[Gi,Gr]], B = 16
// rest-columns of [Xr;Xi], f32 accumulate (v_mfma_f32_16x16x16_f16).
//
// k_pass1 (axes A3..A7; 256 blocks x 1024 thr, 2 tiles/block, 128KB LDS):
//   fill L0=[A4|A5|A6|A7|p|A3] (+fused ||f||^2) -> stage A3 (block-wide,
//   round-4-verbatim, writes L1=[A5|A6|A7|A3|p|A4]) -> stage A4 (block-wide,
//   writes combo-major L2'=[A3|A4|A6|A7|p|A5]) -> then each wave owns combos
//   (A3*8+A4) in [4w,4w+4) = contiguous 8KB: stages A5,A6 (in-place rotation
//   L2'->L3'->L4', wave-private, NO barriers) -> stage A7 fused with global
//   writeout (identity-layout f16 (re,im) dwords). Tile1 global loads are
//   issued after A4's barrier; inter-tile sync = lgkmcnt(0)+raw s_barrier
//   (no vmcnt drain -> prefetch stays in flight).
// k_pass2 (axes A0..A2; 2048 blocks x 256 thr, 32KB LDS = 512 hi x 16 lo):
//   fill L0'=[A1|A0|sp|p|A2] -> stage A2 (block-wide, writes A2-major
//   L1'=[A2|sp|A0|p|A1]) -> wave owns A2 in {2w,2w+1} = 8KB: stage A1
//   (L1'->L2'=[A2|sp|A1|p|A0], private) -> stage A0 + probs = (re^2+im^2)*inv
//   with full-wave stores (plane-select). Block reads/writes the same private
//   d_out region -> race-free.

typedef _Float16 f16;
typedef _Float16 f16x4 __attribute__((ext_vector_type(4)));
typedef float f32x4 __attribute__((ext_vector_type(4)));
typedef unsigned int u32;

__device__ __forceinline__ u32 SW1(u32 a) { return a ^ (((a >> 8) & 0xFu) << 3); }
__device__ __forceinline__ u32 SW2(u32 a) { return a ^ (((a >> 7) & 0xFu) << 3); }

__device__ __forceinline__ u32 PK(float x, float y) {
  return __builtin_bit_cast(u32, __builtin_amdgcn_cvt_pkrtz(x, y));
}

#define FENCE_LDS()                                     \
  do {                                                  \
    asm volatile("s_waitcnt lgkmcnt(0)" ::: "memory");  \
    __builtin_amdgcn_sched_barrier(0);                  \
  } while (0)

#define BARRIER_RAW()                                   \
  do {                                                  \
    asm volatile("s_waitcnt lgkmcnt(0)" ::: "memory");  \
    __builtin_amdgcn_sched_barrier(0);                  \
    __builtin_amdgcn_s_barrier();                       \
  } while (0)

// A fragment for v_mfma_f32_16x16x16_f16: lane holds A[row=l&15][k=(l>>4)*4+e].
// A = [[Gr, -Gi], [Gi, Gr]]; rows 0-7 -> re out, 8-15 -> im out; k<8 hits Xr.
__device__ __forceinline__ f16x4 build_A(const float* __restrict__ gr,
                                         const float* __restrict__ gi, int l) {
  const int row = l & 15, kg = l >> 4;
  const int pg = row & 7, rpl = row >> 3, kpl = kg >> 1;
  f16x4 a;
#pragma unroll
  for (int e = 0; e < 4; ++e) {
    const int j = (kg & 1) * 4 + e;
    const float grv = gr[pg * 8 + j], giv = gi[pg * 8 + j];
    const float v = rpl == 0 ? (kpl == 0 ? grv : -giv) : (kpl == 0 ? giv : grv);
    a[e] = (f16)v;
  }
  return a;
}

__device__ __forceinline__ f32x4 MF(f16x4 A, uint2 bw, f32x4 C) {
  return __builtin_amdgcn_mfma_f32_16x16x16f16(A, __builtin_bit_cast(f16x4, bw),
                                               C, 0, 0, 0);
}

// ---- pass1 block-wide stage. MODE 0: A3 (L0->L1). MODE 1: A4 (L1->L2'). ----
template <int MODE>
__device__ __forceinline__ void p1_bw(char* lb, f16x4 A, int w, int l) {
  const int kg = l >> 4, c = l & 15, c3 = c >> 3, p = kg >> 1;
  const u32 rb = (u32)(w * 512 + c * 32 + kg * 8);
  const f32x4 Z = {0.f, 0.f, 0.f, 0.f};
  f32x4 acc[16];
#pragma unroll
  for (int g = 0; g < 4; ++g) {
#pragma unroll
    for (int m = 0; m < 4; ++m) {
      const int j = (g & 1) + m * 2 + (g >> 1) * 8;
      const uint2 bw = *(const uint2*)(lb + SW1(rb + (u32)j * 8192u));
      acc[g * 4 + m] = MF(A, bw, Z);
    }
  }
  __syncthreads();
#pragma unroll
  for (int g = 0; g < 4; ++g) {
#pragma unroll
    for (int rr = 0; rr < 4; ++rr) {
      const u32 d0 = PK(acc[g * 4 + 0][rr], acc[g * 4 + 1][rr]);
      const u32 d1 = PK(acc[g * 4 + 2][rr], acc[g * 4 + 3][rr]);
      u32 lg;
      if constexpr (MODE == 0) {
        lg = (u32)(((w >> 2) << 14) + (((w & 3) * 2 + c3) << 11) +
                   ((c & 7) << 8) + ((kg & 1) << 7) + (p << 4) +
                   ((g & 1) << 16) + ((g >> 1) << 3) + (rr << 5));
      } else {
        lg = (u32)(((c & 7) << 14) + ((kg & 1) << 13) + (rr << 11) +
                   ((((g & 1) << 2) + (w >> 2)) << 8) +
                   ((((w & 3) << 1) + c3) << 5) + (p << 4) + ((g >> 1) << 3));
      }
      *(uint2*)(lb + SW1(lg)) = make_uint2(d0, d1);
    }
  }
  __syncthreads();
}

// ---- pass1 wave-private stage (A5: L2'->L3', A6: L3'->L4'; same formula) ----
__device__ __forceinline__ void p1_priv(char* lb, f16x4 A, int w, int l) {
  const int kg = l >> 4, c = l & 15, c3 = c >> 3, p = kg >> 1;
  const f32x4 Z = {0.f, 0.f, 0.f, 0.f};
  f32x4 acc[16];
#pragma unroll
  for (int g = 0; g < 4; ++g) {
#pragma unroll
    for (int m = 0; m < 4; ++m) {
      const u32 rb = (u32)(((4 * w + g) << 11) + (((c3 << 2) + m) << 8) +
                           ((c & 7) << 5) + (kg << 3));
      const uint2 bw = *(const uint2*)(lb + SW1(rb));
      acc[g * 4 + m] = MF(A, bw, Z);
    }
  }
  FENCE_LDS();
#pragma unroll
  for (int g = 0; g < 4; ++g) {
#pragma unroll
    for (int rr = 0; rr < 4; ++rr) {
      const u32 d0 = PK(acc[g * 4 + 0][rr], acc[g * 4 + 1][rr]);
      const u32 d1 = PK(acc[g * 4 + 2][rr], acc[g * 4 + 3][rr]);
      const u32 lg = (u32)(((4 * w + g) << 11) + ((c & 7) << 8) +
                           ((((kg & 1) << 2) + rr) << 5) + (p << 4) + (c3 << 3));
      *(uint2*)(lb + SW1(lg)) = make_uint2(d0, d1);
    }
  }
  FENCE_LDS();
}

// ---- pass1 stage A7 fused with intermediate writeout (reads L4') ----
__device__ __forceinline__ void p1_last(char* lb, f16x4 A, int w, int l,
                                        uint4* __restrict__ st, int tile) {
  const int kg = l >> 4, c = l & 15, c3 = c >> 3, p = kg >> 1, kg0 = kg & 1;
  const f32x4 Z = {0.f, 0.f, 0.f, 0.f};
  const size_t ob = (size_t)tile * 8192;
#pragma unroll
  for (int g = 0; g < 4; ++g) {
#pragma unroll
    for (int m = 0; m < 4; ++m) {
      const u32 rb = (u32)(((4 * w + g) << 11) + (((c3 << 2) + m) << 8) +
                           ((c & 7) << 5) + (kg << 3));
      const uint2 bw = *(const uint2*)(lb + SW1(rb));
      const f32x4 a = MF(A, bw, Z);
      const u32 h01 = PK(a[0], a[1]), h23 = PK(a[2], a[3]);
      const u32 q01 = __shfl_xor(h01, 32, 64), q23 = __shfl_xor(h23, 32, 64);
      if (p == 0) {  // partner plane (p=1) holds im parts
        uint4 vv;
        vv.x = (h01 & 0xffffu) | (q01 << 16);
        vv.y = (h01 >> 16) | (q01 & 0xffff0000u);
        vv.z = (h23 & 0xffffu) | (q23 << 16);
        vv.w = (h23 >> 16) | (q23 & 0xffff0000u);
        const int combo = 4 * w + g;          // A3*8+A4
        const int A5v = c3 * 4 + m, A6v = c & 7;
        st[ob + (u32)(combo * 128 + A5v * 16 + A6v * 2 + kg0)] = vv;
      }
    }
  }
}

// ---- pass1 fill: rows 0..3 from pre[], rows 4..7 loaded here ----
__device__ __forceinline__ float p1_fill(char* lb, const float* __restrict__ f,
                                         int tile, int t, const float4* pre) {
  const float4* fin = (const float4*)f + (size_t)tile * 8192;
  float4 hi4[4];
#pragma unroll
  for (int d = 0; d < 4; ++d) hi4[d] = fin[(4 + d) * 1024 + t];
  const u32 fl = (u32)(((t >> 7) << 14) | (((t >> 4) & 7) << 11) |
                       (((t >> 1) & 7) << 8) | ((t & 1) << 7));
  float s = 0.f;
#pragma unroll
  for (int g2 = 0; g2 < 2; ++g2) {
    const float4 v0 = g2 ? hi4[0] : pre[0];
    const float4 v1 = g2 ? hi4[1] : pre[1];
    const float4 v2 = g2 ? hi4[2] : pre[2];
    const float4 v3 = g2 ? hi4[3] : pre[3];
    s += v0.x * v0.x + v0.y * v0.y + v0.z * v0.z + v0.w * v0.w;
    s += v1.x * v1.x + v1.y * v1.y + v1.z * v1.z + v1.w * v1.w;
    s += v2.x * v2.x + v2.y * v2.y + v2.z * v2.z + v2.w * v2.w;
    s += v3.x * v3.x + v3.y * v3.y + v3.z * v3.z + v3.w * v3.w;
#pragma unroll
    for (int q = 0; q < 4; ++q) {
      const float a0 = q == 0 ? v0.x : q == 1 ? v0.y : q == 2 ? v0.z : v0.w;
      const float a1 = q == 0 ? v1.x : q == 1 ? v1.y : q == 2 ? v1.z : v1.w;
      const float a2 = q == 0 ? v2.x : q == 1 ? v2.y : q == 2 ? v2.z : v2.w;
      const float a3 = q == 0 ? v3.x : q == 1 ? v3.y : q == 2 ? v3.z : v3.w;
      const u32 lg = fl + (u32)((q << 5) + (g2 << 3));
      *(uint2*)(lb + SW1(lg)) = make_uint2(PK(a0, a1), PK(a2, a3));
      *(uint2*)(lb + SW1(lg + 16u)) = make_uint2(0u, 0u);  // im plane
    }
  }
  return s;
}

__global__ __launch_bounds__(1024, 4) void k_pass1(
    const float* __restrict__ f, const float* __restrict__ gr,
    const float* __restrict__ gi, uint4* __restrict__ st,
    float* __restrict__ wsp) {
  __shared__ __align__(16) char lb[131072];
  __shared__ float red[16];
  const int t = threadIdx.x, l = t & 63, w = t >> 6, blk = blockIdx.x;
  const f16x4 A = build_A(gr, gi, l);
  float nrm = 0.f;
  float4 pre[4];
  {
    const float4* fin = (const float4*)f + (size_t)(blk * 2) * 8192;
#pragma unroll
    for (int d = 0; d < 4; ++d) pre[d] = fin[d * 1024 + t];
  }
#pragma unroll
  for (int tt = 0; tt < 2; ++tt) {
    const int tile = blk * 2 + tt;
    float s = p1_fill(lb, f, tile, t, pre);
#pragma unroll
    for (int off = 32; off; off >>= 1) s += __shfl_down(s, off, 64);
    if (l == 0) red[w] = s;
    __syncthreads();  // fill + red visible
    if (t == 0) {
      float a = 0.f;
#pragma unroll
      for (int i = 0; i < 16; ++i) a += red[i];
      nrm += a;
    }
    p1_bw<0>(lb, A, w, l);  // A3: L0 -> L1
    p1_bw<1>(lb, A, w, l);  // A4: L1 -> L2' (combo-major)
    if (tt == 0) {          // prefetch tile1 rows 0..3 (held across private phase)
      const float4* fin = (const float4*)f + (size_t)(blk * 2 + 1) * 8192;
#pragma unroll
      for (int d = 0; d < 4; ++d) pre[d] = fin[d * 1024 + t];
    }
    p1_priv(lb, A, w, l);           // A5: L2' -> L3'   (wave-private)
    p1_priv(lb, A, w, l);           // A6: L3' -> L4'   (wave-private)
    p1_last(lb, A, w, l, st, tile); // A7 + writeout    (wave-private)
    if (tt == 0) BARRIER_RAW();     // lgkm-only: prefetch stays in flight
  }
  if (t == 0) wsp[blk] = nrm;
}

// ---------------- pass2 ----------------
__global__ __launch_bounds__(256, 4) void k_pass2(
    const uint4* __restrict__ gp, const float* __restrict__ gr,
    const float* __restrict__ gi, const float* __restrict__ wsp,
    float* __restrict__ out) {
  __shared__ __align__(16) char lb[32768];
  __shared__ float red[4];
  const int t = threadIdx.x, l = t & 63, w = t >> 6;
  const int kg = l >> 4, c = l & 15, kg0 = kg & 1, kg1 = kg >> 1;
  const int b9 = blockIdx.x >> 2, q = blockIdx.x & 3;
  const f16x4 A = build_A(gr, gi, l);
  const f32x4 Z = {0.f, 0.f, 0.f, 0.f};

  float sp_ = wsp[t];  // 256 pass1 block partials
#pragma unroll
  for (int off = 32; off; off >>= 1) sp_ += __shfl_down(sp_, off, 64);
  if (l == 0) red[w] = sp_;

  // ---- fill L0' = [A1|A0|sp|p|A2] from intermediate ----
  {
    const int z = t >> 2, u = t & 3;
    const int A0v = z >> 3, A1v = z & 7;
#pragma unroll
    for (int a2g = 0; a2g < 2; ++a2g) {
      uint4 raw[4];
#pragma unroll
      for (int d = 0; d < 4; ++d)
        raw[d] = gp[(size_t)(z * 8 + a2g * 4 + d) * 8192 +
                    (u32)(b9 * 16 + q * 4 + u)];
#pragma unroll
      for (int v = 0; v < 4; ++v) {
        const u32 w0 = v == 0 ? raw[0].x : v == 1 ? raw[0].y : v == 2 ? raw[0].z : raw[0].w;
        const u32 w1 = v == 0 ? raw[1].x : v == 1 ? raw[1].y : v == 2 ? raw[1].z : raw[1].w;
        const u32 w2 = v == 0 ? raw[2].x : v == 1 ? raw[2].y : v == 2 ? raw[2].z : raw[2].w;
        const u32 w3 = v == 0 ? raw[3].x : v == 1 ? raw[3].y : v == 2 ? raw[3].z : raw[3].w;
        const int spv = u * 4 + v;
        const u32 base = (u32)((A1v << 12) + (A0v << 9) + (spv << 5) + (a2g << 3));
        *(uint2*)(lb + SW2(base)) =
            make_uint2((w0 & 0xffffu) | (w1 << 16), (w2 & 0xffffu) | (w3 << 16));
        *(uint2*)(lb + SW2(base + 16u)) =
            make_uint2((w0 >> 16) | (w1 & 0xffff0000u), (w2 >> 16) | (w3 & 0xffff0000u));
      }
    }
  }
  __syncthreads();
  const float inv = 1.0f / (red[0] + red[1] + red[2] + red[3]);

  // ---- stage A2 (block-wide): L0' -> L1' = [A2|sp|A0|p|A1] ----
  {
    f32x4 acc[16];
#pragma unroll
    for (int g = 0; g < 4; ++g) {
#pragma unroll
      for (int m = 0; m < 4; ++m) {
        const int j = (g & 1) + m * 2 + (g >> 1) * 8;
        const u32 rb = (u32)(((j >> 1) << 12) + ((((j & 1) << 2) + w) << 9) +
                             (c << 5) + (kg << 3));
        const uint2 bw = *(const uint2*)(lb + SW2(rb));
        acc[g * 4 + m] = MF(A, bw, Z);
      }
    }
    __syncthreads();
#pragma unroll
    for (int g = 0; g < 4; ++g) {
#pragma unroll
      for (int rr = 0; rr < 4; ++rr) {
        const u32 d0 = PK(acc[g * 4 + 0][rr], acc[g * 4 + 1][rr]);
        const u32 d1 = PK(acc[g * 4 + 2][rr], acc[g * 4 + 3][rr]);
        const u32 lg = (u32)((((kg0 << 2) + rr) << 12) + (c << 8) +
                             ((((g & 1) << 2) + w) << 5) + (kg1 << 4) +
                             ((g >> 1) << 3));
        *(uint2*)(lb + SW2(lg)) = make_uint2(d0, d1);
      }
    }
    __syncthreads();
  }

  const int c0 = c & 1, ch = c >> 1;

  // ---- stage A1 (wave-private, A2 in {2w,2w+1}): L1' -> L2' = [A2|sp|A1|p|A0]
  {
    f32x4 acc[16];
#pragma unroll
    for (int G = 0; G < 4; ++G) {
#pragma unroll
      for (int m = 0; m < 4; ++m) {
        const u32 rb = (u32)(((2 * w + (G >> 1)) << 12) +
                             ((((G & 1) << 3) + ch) << 8) +
                             (((c0 << 2) + m) << 5) + (kg << 3));
        const uint2 bw = *(const uint2*)(lb + SW2(rb));
        acc[G * 4 + m] = MF(A, bw, Z);
      }
    }
    FENCE_LDS();
#pragma unroll
    for (int G = 0; G < 4; ++G) {
#pragma unroll
      for (int rr = 0; rr < 4; ++rr) {
        const u32 d0 = PK(acc[G * 4 + 0][rr], acc[G * 4 + 1][rr]);
        const u32 d1 = PK(acc[G * 4 + 2][rr], acc[G * 4 + 3][rr]);
        const u32 lg = (u32)(((2 * w + (G >> 1)) << 12) +
                             ((((G & 1) << 3) + ch) << 8) +
                             (((kg0 << 2) + rr) << 5) + (kg1 << 4) + (c0 << 3));
        *(uint2*)(lb + SW2(lg)) = make_uint2(d0, d1);
      }
    }
    FENCE_LDS();
  }

  // ---- stage A0 (wave-private) + probs writeout ----
  {
    const u32 nbase = (u32)(b9 * 64 + q * 16);
#pragma unroll
    for (int G = 0; G < 4; ++G) {
#pragma unroll
      for (int m = 0; m < 4; ++m) {
        const u32 rb = (u32)(((2 * w + (G >> 1)) << 12) +
                             ((((G & 1) << 3) + ch) << 8) +
                             (((c0 << 2) + m) << 5) + (kg << 3));
        const uint2 bw = *(const uint2*)(lb + SW2(rb));
        const f32x4 a = MF(A, bw, Z);
        float qv0 = a[0] * a[0]; qv0 += __shfl_xor(qv0, 32, 64);
        float qv1 = a[1] * a[1]; qv1 += __shfl_xor(qv1, 32, 64);
        float qv2 = a[2] * a[2]; qv2 += __shfl_xor(qv2, 32, 64);
        float qv3 = a[3] * a[3]; qv3 += __shfl_xor(qv3, 32, 64);
        const int A1v = c0 * 4 + m, A2v = 2 * w + (G >> 1);
        const int spv = (G & 1) * 8 + ch;
        const size_t base = ((size_t)A1v << 18) + ((size_t)A2v << 15) +
                            (size_t)(nbase + spv);
        {  // h = 0: rr_eff = kg1*2
          const float val = (kg1 ? qv2 : qv0) * inv;
          const size_t A0v = (size_t)(kg0 * 4 + kg1 * 2);
          out[base + (A0v << 21)] = val;
        }
        {  // h = 1: rr_eff = kg1*2 + 1
          const float val = (kg1 ? qv3 : qv1) * inv;
          const size_t A0v = (size_t)(kg0 * 4 + kg1 * 2 + 1);
          out[base + (A0v << 21)] = val;
        }
      }
    }
  }
}

extern "C" void kernel_launch(void* const* d_in, const int* in_sizes, int n_in,
                              void* d_out, int out_size, void* d_ws,
                              size_t ws_size, hipStream_t stream) {
  (void)in_sizes; (void)n_in; (void)out_size; (void)ws_size;
  const float* f = (const float*)d_in[0];
  const float* gr = (const float*)d_in[1];
  const float* gi = (const float*)d_in[2];
  float* wsp = (float*)d_ws;  // 256 floats

  k_pass1<<<dim3(256), dim3(1024), 0, stream>>>(f, gr, gi, (uint4*)d_out, wsp);
  k_pass2<<<dim3(2048), dim3(256), 0, stream>>>((const uint4*)d_out, gr, gi,
                                                wsp, (float*)d_out);
}

// Round 7
// 76.854 us; speedup vs baseline: 1.3037x; 1.3037x over previous
//
#include <hip/hip_runtime.h>

// probs = |U^{x8} f|^2 / ||f||^2, U = 8x8 complex gate on each of 8 qubit triples.
// MFMA: per 3-qubit axis, D = A*B, A(16x16 f16) = [[Gr,-Gi],[Gi,Gr]], B = 16
// rest-columns of [Xr;Xi], f32 accumulate (v_mfma_f32_16x16x16_f16).
//
// Round-4 structure (best verified), with two surgical changes:
//  * fill writes ONLY the re plane (im-plane zeros dropped) -> half the fill
//    LDS writes and their 4-way bank conflicts; all 8 global float4 loads
//    hoisted ahead of packing.
//  * stage A3 (first LDS stage) reads the im plane as literal zero via a
//    predicated read (kg>=2 lanes contribute 0), matching the dropped fill.
//
// k_pass1: axes A3..A7 (low 15 bits). 512 blocks x 1024 thr, 128KB LDS tile,
//   5 MFMA stages (uniform digit rotation on layout [e3|e2|e1|e0|p|k], swizzle
//   SW1); fill fuses ||f||^2 partials -> d_ws; stage A7 fused with writeout of
//   the interleaved (re,im) f16 intermediate to d_out (natural order).
// k_pass2: axes A0..A2. 2048 blocks x 256 thr, 32KB LDS (512 hi x 16 lo),
//   layout [s1|s0|sp|p|k] with swizzle SW2; 2 LDS stages + final stage fused
//   with probs = (re^2+im^2)*inv writeout. Each block reads/writes the same
//   private region of d_out -> race-free.

typedef _Float16 f16;
typedef _Float16 f16x4 __attribute__((ext_vector_type(4)));
typedef float f32x4 __attribute__((ext_vector_type(4)));
typedef unsigned int u32;
typedef unsigned short u16;

__device__ __forceinline__ u32 SW1(u32 a) { return a ^ (((a >> 8) & 0xFu) << 3); }
__device__ __forceinline__ u32 SW2(u32 a) { return a ^ (((a >> 7) & 0x7u) << 4); }

__device__ __forceinline__ u32 PK(float x, float y) {
  return __builtin_bit_cast(u32, __builtin_amdgcn_cvt_pkrtz(x, y));
}

// A fragment for v_mfma_f32_16x16x16_f16: lane holds A[row=l&15][k=(l>>4)*4+e].
// A = [[Gr, -Gi], [Gi, Gr]]; rows 0-7 -> re out, 8-15 -> im out; k<8 hits Xr.
__device__ __forceinline__ f16x4 build_A(const float* __restrict__ gr,
                                         const float* __restrict__ gi, int l) {
  const int row = l & 15, kg = l >> 4;
  const int pg = row & 7, rpl = row >> 3, kpl = kg >> 1;
  f16x4 a;
#pragma unroll
  for (int e = 0; e < 4; ++e) {
    const int j = (kg & 1) * 4 + e;
    const float grv = gr[pg * 8 + j], giv = gi[pg * 8 + j];
    const float v = rpl == 0 ? (kpl == 0 ? grv : -giv) : (kpl == 0 ? giv : grv);
    a[e] = (f16)v;
  }
  return a;
}

__device__ __forceinline__ f32x4 MF(f16x4 A, uint2 bw, f32x4 C) {
  return __builtin_amdgcn_mfma_f32_16x16x16f16(A, __builtin_bit_cast(f16x4, bw),
                                               C, 0, 0, 0);
}

// One in-LDS gate stage (read all -> barrier -> write all -> barrier).
// FIRST=true: im-plane (kg>=2) reads replaced by 0 (fill wrote re only).
template <bool FIRST>
__device__ __forceinline__ void lds_stage(char* lb, f16x4 A, int w, int l) {
  const int kg = l >> 4, c = l & 15, c3 = c >> 3, p = kg >> 1;
  const u32 rb = (u32)(w * 512 + c * 32 + kg * 8);
  const f32x4 Z = {0.f, 0.f, 0.f, 0.f};
  f32x4 acc[16];
#pragma unroll
  for (int g = 0; g < 4; ++g) {
#pragma unroll
    for (int m = 0; m < 4; ++m) {
      const int j = (g & 1) + m * 2 + (g >> 1) * 8;
      uint2 bw = make_uint2(0u, 0u);
      if (!FIRST || kg < 2)
        bw = *(const uint2*)(lb + SW1(rb + (u32)j * 8192u));
      acc[g * 4 + m] = MF(A, bw, Z);
    }
  }
  __syncthreads();  // all reads everywhere done -> in-place writes safe
  const u32 wl = (u32)(((w >> 2) << 14) + (((w & 3) * 2 + c3) << 11) +
                       ((c & 7) << 8) + ((kg & 1) << 7) + (p << 4));
#pragma unroll
  for (int g = 0; g < 4; ++g) {
#pragma unroll
    for (int rr = 0; rr < 4; ++rr) {
      const u32 d0 = PK(acc[g * 4 + 0][rr], acc[g * 4 + 1][rr]);
      const u32 d1 = PK(acc[g * 4 + 2][rr], acc[g * 4 + 3][rr]);
      const u32 lg = wl + (u32)(((g & 1) << 16) + ((g >> 1) << 3) + (rr << 5));
      *(uint2*)(lb + SW1(lg)) = make_uint2(d0, d1);
    }
  }
  __syncthreads();
}

__global__ __launch_bounds__(1024, 4) void k_pass1(
    const float* __restrict__ f, const float* __restrict__ gr,
    const float* __restrict__ gi, uint4* __restrict__ st,
    float* __restrict__ wsp) {
  __shared__ __align__(16) char lb[131072];
  __shared__ float red[16];
  const int t = threadIdx.x, l = t & 63, w = t >> 6, blk = blockIdx.x;
  const int kg = l >> 4, c = l & 15, c3 = c >> 3, p = kg >> 1;
  const f16x4 A = build_A(gr, gi, l);
  const f32x4 Z = {0.f, 0.f, 0.f, 0.f};

  // ---- fill L(0): [A4|A5|A6|A7|p|A3], re plane only; fused ||f||^2 ----
  float s = 0.f;
  {
    const float4* fin = (const float4*)f + (size_t)blk * 8192;
    float4 vv[8];
#pragma unroll
    for (int d = 0; d < 8; ++d) vv[d] = fin[d * 1024 + t];
#pragma unroll
    for (int d = 0; d < 8; ++d)
      s += vv[d].x * vv[d].x + vv[d].y * vv[d].y + vv[d].z * vv[d].z +
           vv[d].w * vv[d].w;
    const u32 fl = (u32)(((t >> 7) << 14) + (((t >> 4) & 7) << 11) +
                         (((t >> 1) & 7) << 8) + ((t & 1) << 7));
#pragma unroll
    for (int g2 = 0; g2 < 2; ++g2) {
#pragma unroll
      for (int q = 0; q < 4; ++q) {
        const float a0 = q == 0 ? vv[g2 * 4 + 0].x : q == 1 ? vv[g2 * 4 + 0].y
                       : q == 2 ? vv[g2 * 4 + 0].z : vv[g2 * 4 + 0].w;
        const float a1 = q == 0 ? vv[g2 * 4 + 1].x : q == 1 ? vv[g2 * 4 + 1].y
                       : q == 2 ? vv[g2 * 4 + 1].z : vv[g2 * 4 + 1].w;
        const float a2 = q == 0 ? vv[g2 * 4 + 2].x : q == 1 ? vv[g2 * 4 + 2].y
                       : q == 2 ? vv[g2 * 4 + 2].z : vv[g2 * 4 + 2].w;
        const float a3 = q == 0 ? vv[g2 * 4 + 3].x : q == 1 ? vv[g2 * 4 + 3].y
                       : q == 2 ? vv[g2 * 4 + 3].z : vv[g2 * 4 + 3].w;
        const u32 lg = fl + (u32)((q << 5) + (g2 << 3));
        *(uint2*)(lb + SW1(lg)) = make_uint2(PK(a0, a1), PK(a2, a3));
        // im plane intentionally NOT written (stage A3 reads it as 0)
      }
    }
  }
#pragma unroll
  for (int off = 32; off; off >>= 1) s += __shfl_down(s, off, 64);
  if (l == 0) red[w] = s;
  __syncthreads();  // fill + red visible
  if (t == 0) {
    float a = 0.f;
#pragma unroll
    for (int i = 0; i < 16; ++i) a += red[i];
    wsp[blk] = a;
  }

  lds_stage<true>(lb, A, w, l);   // A3 (im read as 0)
  lds_stage<false>(lb, A, w, l);  // A4
  lds_stage<false>(lb, A, w, l);  // A5
  lds_stage<false>(lb, A, w, l);  // A6

  // ---- stage A7 fused with writeout (identity-layout intermediate) ----
  // L4 = [A3|A4|A5|A6|p|A7]: A3=j>>1, A4=(j&1)*4+(w>>2), A5=(w&3)*2+c3, A6=c&7
  const u32 rb = (u32)(w * 512 + c * 32 + kg * 8);
  const size_t ob = (size_t)blk * 8192;  // uint4 units
#pragma unroll
  for (int j = 0; j < 16; ++j) {
    const uint2 bw = *(const uint2*)(lb + SW1(rb + (u32)j * 8192u));
    const f32x4 a = MF(A, bw, Z);
    const u32 h01 = PK(a[0], a[1]), h23 = PK(a[2], a[3]);
    const u32 q01 = __shfl_xor(h01, 32, 64), q23 = __shfl_xor(h23, 32, 64);
    if (p == 0) {  // partner (p=1) holds im parts
      const int A3 = j >> 1, A4 = (j & 1) * 4 + (w >> 2), A5 = (w & 3) * 2 + c3;
      uint4 vv;
      vv.x = (h01 & 0xffffu) | (q01 << 16);
      vv.y = (h01 >> 16) | (q01 & 0xffff0000u);
      vv.z = (h23 & 0xffffu) | (q23 << 16);
      vv.w = (h23 >> 16) | (q23 & 0xffff0000u);
      st[ob + (u32)(((A3 * 64 + A4 * 8 + A5) << 4) + ((c & 7) << 1) + (kg & 1))] = vv;
    }
  }
}

// ---------------- pass2: 32KB tile, 4 waves (round-4 verbatim) ----------------
// halfword layout h = s1*2048 + s0*256 + sp*16 + p*8 + k  (byte = 2h, SW2).
// L0: k=A2,s0=A0,s1=A1 -> stage A2 -> L1: k=A1,s0=A2,s1=A0 -> stage A1 ->
// L2: k=A0,s0=A1,s1=A2 -> final stage A0 + probs.
__device__ __forceinline__ void p2_stage(char* lb, f16x4 A, int w, int l) {
  const int kg = l >> 4, c = l & 15, pp = kg >> 1;
  const f32x4 Z = {0.f, 0.f, 0.f, 0.f};
  f32x4 acc[16];
#pragma unroll
  for (int g = 0; g < 4; ++g) {
#pragma unroll
    for (int m = 0; m < 4; ++m) {
      const int j = (g & 1) + m * 2 + (g >> 1) * 8;
      const u32 rb = (u32)(j * 2048 + w * 512 + c * 32 + kg * 8);
      const uint2 bw = *(const uint2*)(lb + SW2(rb));
      acc[g * 4 + m] = MF(A, bw, Z);
    }
  }
  __syncthreads();
  // packed b128 writes: for (pe,rr), halfword slots k'=j>>1 are consecutive
#pragma unroll
  for (int pe = 0; pe < 2; ++pe) {
#pragma unroll
    for (int rr = 0; rr < 4; ++rr) {
      uint4 vv;
      vv.x = PK(acc[pe * 4 + 0][rr], acc[pe * 4 + 1][rr]);
      vv.y = PK(acc[pe * 4 + 2][rr], acc[pe * 4 + 3][rr]);
      vv.z = PK(acc[(2 + pe) * 4 + 0][rr], acc[(2 + pe) * 4 + 1][rr]);
      vv.w = PK(acc[(2 + pe) * 4 + 2][rr], acc[(2 + pe) * 4 + 3][rr]);
      const u32 wb = (u32)((pe * 4 + w) * 4096 + ((kg & 1) * 4 + rr) * 512 +
                           c * 32 + pp * 16);
      *(uint4*)(lb + SW2(wb)) = vv;
    }
  }
  __syncthreads();
}

__global__ __launch_bounds__(256, 4) void k_pass2(
    const uint4* gp, const float* __restrict__ gr, const float* __restrict__ gi,
    const float* __restrict__ wsp, float* out) {
  __shared__ __align__(16) char lb[32768];
  __shared__ float red[4];
  const int t = threadIdx.x, l = t & 63, w = t >> 6;
  const int kg = l >> 4, c = l & 15, pp = kg >> 1;
  const int b9 = blockIdx.x >> 2, q = blockIdx.x & 3;
  const f16x4 A = build_A(gr, gi, l);
  const f32x4 Z = {0.f, 0.f, 0.f, 0.f};

  // norm: reduce pass1 partials (deterministic)
  float sp_ = wsp[t] + wsp[t + 256];
#pragma unroll
  for (int off = 32; off; off >>= 1) sp_ += __shfl_down(sp_, off, 64);
  if (l == 0) red[w] = sp_;

  // ---- fill: 4-hi-grouped uint4 reads -> packed b64 plane writes ----
  // element n = hi*2^15 + b9*64 + q*16 + sp; uint4 idx = hi*8192 + b9*16 + q*4 + u
  {
    const int z = t >> 2, u = t & 3;
    const int A1 = z & 7, A0 = z >> 3;
#pragma unroll
    for (int a2g = 0; a2g < 2; ++a2g) {
      uint4 raw[4];
#pragma unroll
      for (int d = 0; d < 4; ++d)
        raw[d] = gp[(size_t)(z * 8 + 4 * a2g + d) * 8192 + (u32)(b9 * 16 + q * 4 + u)];
#pragma unroll
      for (int v = 0; v < 4; ++v) {
        const u32 w0 = v == 0 ? raw[0].x : v == 1 ? raw[0].y : v == 2 ? raw[0].z : raw[0].w;
        const u32 w1 = v == 0 ? raw[1].x : v == 1 ? raw[1].y : v == 2 ? raw[1].z : raw[1].w;
        const u32 w2 = v == 0 ? raw[2].x : v == 1 ? raw[2].y : v == 2 ? raw[2].z : raw[2].w;
        const u32 w3 = v == 0 ? raw[3].x : v == 1 ? raw[3].y : v == 2 ? raw[3].z : raw[3].w;
        const int sp = u * 4 + v;
        const u32 base = (u32)(A1 * 4096 + A0 * 512 + sp * 32 + 8 * a2g);
        // re plane (p=0): lo halves, k = A2 = 4*a2g + d consecutive
        *(uint2*)(lb + SW2(base)) =
            make_uint2((w0 & 0xffffu) | (w1 << 16), (w2 & 0xffffu) | (w3 << 16));
        // im plane (p=1)
        *(uint2*)(lb + SW2(base + 16u)) =
            make_uint2((w0 >> 16) | (w1 & 0xffff0000u), (w2 >> 16) | (w3 & 0xffff0000u));
      }
    }
  }
  __syncthreads();
  const float inv = 1.0f / (red[0] + red[1] + red[2] + red[3]);

  p2_stage(lb, A, w, l);  // A2
  p2_stage(lb, A, w, l);  // A1

  // ---- final stage A0 + probs writeout ----
  // L2: A2 = j>>1, A1 = (j&1)*4+w, sp = c; rows: p=kg>>1, A0 = (kg&1)*4+rr
#pragma unroll
  for (int j = 0; j < 16; ++j) {
    const u32 rb = (u32)(j * 2048 + w * 512 + c * 32 + kg * 8);
    const uint2 bw = *(const uint2*)(lb + SW2(rb));
    const f32x4 a = MF(A, bw, Z);
    const int A2 = j >> 1, A1 = (j & 1) * 4 + w;
    const size_t gb = ((size_t)A1 << 18) + ((size_t)A2 << 15) +
                      (u32)(b9 * 64 + q * 16 + c);
#pragma unroll
    for (int rr = 0; rr < 4; ++rr) {
      float qv = a[rr] * a[rr];
      qv += __shfl_xor(qv, 32, 64);  // re^2 + im^2 from partner plane
      if ((rr >> 1) == pp) {         // p=0 stores rr 0,1; p=1 stores rr 2,3
        const size_t A0 = (size_t)((kg & 1) * 4 + rr);
        out[gb + (A0 << 21)] = qv * inv;
      }
    }
  }
}

extern "C" void kernel_launch(void* const* d_in, const int* in_sizes, int n_in,
                              void* d_out, int out_size, void* d_ws,
                              size_t ws_size, hipStream_t stream) {
  (void)in_sizes; (void)n_in; (void)out_size; (void)ws_size;
  const float* f = (const float*)d_in[0];
  const float* gr = (const float*)d_in[1];
  const float* gi = (const float*)d_in[2];
  float* wsp = (float*)d_ws;  // 512 floats

  k_pass1<<<dim3(512), dim3(1024), 0, stream>>>(f, gr, gi, (uint4*)d_out, wsp);
  k_pass2<<<dim3(2048), dim3(256), 0, stream>>>((const uint4*)d_out, gr, gi,
                                                wsp, (float*)d_out);
}